// Round 1
// baseline (388.850 us; speedup 1.0000x reference)
//
#include <hip/hip_runtime.h>
#include <hip/hip_bf16.h>

using bf16 = __hip_bfloat16;

// ---------------- helpers ----------------
__device__ inline float b2f_raw(unsigned short u) {
    return __uint_as_float(((unsigned)u) << 16);
}
__device__ inline float4 load4(const float* p) {
    return *reinterpret_cast<const float4*>(p);
}
__device__ inline float4 load4(const bf16* p) {
    const ushort4 u = *reinterpret_cast<const ushort4*>(p);
    float4 f;
    f.x = b2f_raw(u.x); f.y = b2f_raw(u.y); f.z = b2f_raw(u.z); f.w = b2f_raw(u.w);
    return f;
}
__device__ inline void store1(float* p, float v) { *p = v; }
__device__ inline void store1(bf16* p, float v) { *p = __float2bfloat16(v); }

__device__ __constant__ int c_dil[8] = {1, 2, 4, 8, 1, 2, 4, 8};

// ---------------- GEMM: C(MxN) = A(MxK) * Bw(NxK)^T + bias(N) ----------------
// 64x64 tile, BK=16, 256 threads, 4x4 per thread. M,N div by 64; K div by 16.
template <typename TA, typename TC>
__global__ __launch_bounds__(256) void gemm_atb(
    const TA* __restrict__ A, const float* __restrict__ Bw,
    const float* __restrict__ bias, TC* __restrict__ C,
    int M, int N, int K)
{
    __shared__ float As[16][68];  // [k][m], pad to 68 (16B-aligned rows)
    __shared__ float Bs[16][68];  // [k][n]

    const int bm = blockIdx.y * 64;
    const int bn = blockIdx.x * 64;
    const int tid = threadIdx.x;
    const int tx = tid & 15;      // col group
    const int ty = tid >> 4;      // row group
    const int lr = tid >> 2;      // load row 0..63
    const int lc = (tid & 3) << 2; // load col 0,4,8,12

    float acc[4][4] = {};

    for (int k0 = 0; k0 < K; k0 += 16) {
        float4 av = load4(A  + (size_t)(bm + lr) * K + (k0 + lc));
        float4 bv = load4(Bw + (size_t)(bn + lr) * K + (k0 + lc));
        As[lc + 0][lr] = av.x; As[lc + 1][lr] = av.y;
        As[lc + 2][lr] = av.z; As[lc + 3][lr] = av.w;
        Bs[lc + 0][lr] = bv.x; Bs[lc + 1][lr] = bv.y;
        Bs[lc + 2][lr] = bv.z; Bs[lc + 3][lr] = bv.w;
        __syncthreads();

#pragma unroll
        for (int kk = 0; kk < 16; ++kk) {
            const float4 ra = *reinterpret_cast<const float4*>(&As[kk][ty * 4]);
            const float4 rb = *reinterpret_cast<const float4*>(&Bs[kk][tx * 4]);
            const float a_[4] = {ra.x, ra.y, ra.z, ra.w};
            const float b_[4] = {rb.x, rb.y, rb.z, rb.w};
#pragma unroll
            for (int i = 0; i < 4; ++i)
#pragma unroll
                for (int j = 0; j < 4; ++j)
                    acc[i][j] = fmaf(a_[i], b_[j], acc[i][j]);
        }
        __syncthreads();
    }

#pragma unroll
    for (int i = 0; i < 4; ++i) {
        const int row = bm + ty * 4 + i;
#pragma unroll
        for (int j = 0; j < 4; ++j) {
            const int col = bn + tx * 4 + j;
            store1(C + (size_t)row * N + col, acc[i][j] + bias[col]);
        }
    }
}

// ---------------- local attention stitch ----------------
// One wave per (b,l,h) task; lane = o (0..63).
// logits[kk] = dot64(Q[b,l,h,:], Kp[b, l+(kk-2)*d, h, kk, :])  (0 if OOB)
// attn = softmax(logits) . V / 8
__global__ __launch_bounds__(256) void attn_k(
    const float* __restrict__ Q, const bf16* __restrict__ Kp,
    const bf16* __restrict__ Vp, float* __restrict__ attn)
{
    const int lane = threadIdx.x & 63;
    const int wave = threadIdx.x >> 6;
    const int task = blockIdx.x * 4 + wave;  // 0..32767
    const int h  = task & 7;
    const int bl = task >> 3;                // b*L + l
    const int l  = bl & 2047;
    const int d  = c_dil[h];

    const float q = Q[(size_t)bl * 512 + h * 64 + lane];

    float logits[5];
    float vvals[5];
#pragma unroll
    for (int kk = 0; kk < 5; ++kk) {
        const int pos = l + (kk - 2) * d;
        const bool ok = (pos >= 0) && (pos < 2048);
        float kv = 0.f, vv = 0.f;
        if (ok) {
            const size_t idx = (size_t)(bl - l + pos) * 2560 + (h * 5 + kk) * 64 + lane;
            kv = __bfloat162float(Kp[idx]);
            vv = __bfloat162float(Vp[idx]);
        }
        vvals[kk] = vv;
        float lg = q * kv;
#pragma unroll
        for (int s = 32; s; s >>= 1) lg += __shfl_xor(lg, s);
        logits[kk] = lg;  // OOB taps give exactly 0 (k-vector is zero), matching reference
    }

    float mx = logits[0];
#pragma unroll
    for (int kk = 1; kk < 5; ++kk) mx = fmaxf(mx, logits[kk]);
    float e[5], ssum = 0.f;
#pragma unroll
    for (int kk = 0; kk < 5; ++kk) { e[kk] = __expf(logits[kk] - mx); ssum += e[kk]; }
    const float inv = 1.f / ssum;
    float acc = 0.f;
#pragma unroll
    for (int kk = 0; kk < 5; ++kk) acc += e[kk] * vvals[kk];
    acc *= inv * 0.125f;  // / sqrt(64)

    attn[(size_t)bl * 512 + h * 64 + lane] = acc;
}

// ---------------- launch ----------------
extern "C" void kernel_launch(void* const* d_in, const int* in_sizes, int n_in,
                              void* d_out, int out_size, void* d_ws, size_t ws_size,
                              hipStream_t stream)
{
    const float* x   = (const float*)d_in[0];
    const float* q_w = (const float*)d_in[1];
    const float* q_b = (const float*)d_in[2];
    const float* k_w = (const float*)d_in[3];
    const float* k_b = (const float*)d_in[4];
    const float* v_w = (const float*)d_in[5];
    const float* v_b = (const float*)d_in[6];
    const float* o_w = (const float*)d_in[7];
    const float* o_b = (const float*)d_in[8];
    float* out = (float*)d_out;

    const int M = 4096;  // B*L

    // workspace layout: [Q f32][attn f32][Kp bf16][Vp bf16]  = 8+8+20+20 MB
    float* Q    = (float*)d_ws;
    float* attn = Q + (size_t)M * 512;
    bf16*  Kp   = (bf16*)(attn + (size_t)M * 512);
    bf16*  Vp   = Kp + (size_t)M * 2560;

    dim3 blk(256);
    gemm_atb<float, float><<<dim3(512 / 64,  M / 64), blk, 0, stream>>>(x, q_w, q_b, Q,  M, 512,  512);
    gemm_atb<float, bf16 ><<<dim3(2560 / 64, M / 64), blk, 0, stream>>>(x, k_w, k_b, Kp, M, 2560, 512);
    gemm_atb<float, bf16 ><<<dim3(2560 / 64, M / 64), blk, 0, stream>>>(x, v_w, v_b, Vp, M, 2560, 512);
    attn_k<<<dim3(32768 / 4), blk, 0, stream>>>(Q, Kp, Vp, attn);
    gemm_atb<float, float><<<dim3(512 / 64,  M / 64), blk, 0, stream>>>(attn, o_w, o_b, out, M, 512, 512);
}

// Round 2
// 138.313 us; speedup vs baseline: 2.8114x; 2.8114x over previous
//
#include <hip/hip_runtime.h>
#include <hip/hip_bf16.h>

using bf16 = __hip_bfloat16;
typedef __attribute__((ext_vector_type(8))) short short8;
typedef __attribute__((ext_vector_type(4))) float f32x4;

__device__ __constant__ int c_dil[8] = {1, 2, 4, 8, 1, 2, 4, 8};

__device__ inline void store1(float* p, float v) { *p = v; }
__device__ inline void store1(bf16* p, float v) { *p = __float2bfloat16(v); }

// async global->LDS, 16 B per lane, LDS dest = wave-uniform base + lane*16
__device__ inline void gload_lds16(const void* g, void* l) {
    __builtin_amdgcn_global_load_lds(
        (const __attribute__((address_space(1))) unsigned int*)g,
        (__attribute__((address_space(3))) unsigned int*)l, 16, 0, 0);
}

// ---------------- f32 -> bf16 convert (optionally hi/lo split) ----------------
// src rows are 512 floats; dst rows are `ld` bf16 (hi at col c, lo at col 512+c).
__global__ __launch_bounds__(256) void conv_split(
    const float* __restrict__ src, bf16* __restrict__ dst, int ld, int split)
{
    const int i = (blockIdx.x * 256 + threadIdx.x) * 4;
    const float4 v = *reinterpret_cast<const float4*>(src + i);
    const int r = i >> 9, c = i & 511;
    bf16* d = dst + (size_t)r * ld + c;
    const float vv[4] = {v.x, v.y, v.z, v.w};
#pragma unroll
    for (int j = 0; j < 4; ++j) {
        const bf16 h = __float2bfloat16(vv[j]);
        d[j] = h;
        if (split) d[512 + j] = __float2bfloat16(vv[j] - __bfloat162float(h));
    }
}

__global__ __launch_bounds__(256) void pack_bias(
    const float* __restrict__ qb, const float* __restrict__ kb, float* __restrict__ dst)
{
    const int i = blockIdx.x * 256 + threadIdx.x;  // 3072
    dst[i] = (i < 512) ? qb[i] : kb[i - 512];
}

// ---------------- MFMA GEMM: C(MxN) = A(M x lda) * W(N x ldw)^T + bias ----------------
// m97 structure: BM=128, BK=32, 256 threads (4 waves, 2x2), per-wave 64 x BN/2.
// K per k-block is 512; kblocks=3 runs the split schedule:
//   kb0: A[hi]*W[hi], kb1: A[lo]*W[hi], kb2: A[hi]*W[lo]   (A=[hi|lo], W=[whi|wlo])
template <int BN, typename TC>
__global__ __launch_bounds__(256) void mfma_gemm(
    const bf16* __restrict__ A, const bf16* __restrict__ W,
    const float* __restrict__ bias, TC* __restrict__ C,
    int M, int N, int lda, int ldw, int kblocks)
{
    constexpr int BM = 128;
    constexpr int WN = BN / 2;
    constexpr int NF = WN / 16;
    __shared__ short As[BM * 32];   // [m][k], 64 B rows
    __shared__ short Bs[BN * 32];   // [n][k]

    const int tid  = threadIdx.x;
    const int wid  = tid >> 6;
    const int lane = tid & 63;
    const int bm = blockIdx.y * BM;
    const int bn = blockIdx.x * BN;
    const int wr = wid >> 1;        // 0..1
    const int wc = wid & 1;         // 0..1

    f32x4 acc[4][NF];
#pragma unroll
    for (int i = 0; i < 4; ++i)
#pragma unroll
        for (int j = 0; j < NF; ++j) acc[i][j] = f32x4{0.f, 0.f, 0.f, 0.f};

    const int lr16 = lane & 15;
    const int lk   = (lane >> 4) * 8;     // k-elem offset 0,8,16,24
    const int srow = lane >> 2;           // staging row within chunk (0..15)
    const int scol = (lane & 3) * 16;     // staging byte within row

    const int nsteps = kblocks * 16;
    for (int s = 0; s < nsteps; ++s) {
        const int kb  = s >> 4;
        const int kk0 = (s & 15) * 32;
        const int ak0 = kk0 + ((kb == 1) ? 512 : 0);
        const int wk0 = kk0 + ((kb == 2) ? 512 : 0);

        // stage A (8 chunks of 16 rows) + B (BN/16 chunks), round-robin over waves
        for (int c = wid; c < 8 + BN / 16; c += 4) {
            if (c < 8) {
                const char* src = (const char*)A +
                    ((size_t)(bm + c * 16 + srow) * lda + ak0) * 2 + scol;
                gload_lds16(src, (char*)As + c * 1024);
            } else {
                const int cb = c - 8;
                const char* src = (const char*)W +
                    ((size_t)(bn + cb * 16 + srow) * ldw + wk0) * 2 + scol;
                gload_lds16(src, (char*)Bs + cb * 1024);
            }
        }
        __syncthreads();

        short8 af[4];
#pragma unroll
        for (int m = 0; m < 4; ++m)
            af[m] = *(const short8*)&As[(wr * 64 + m * 16 + lr16) * 32 + lk];
        short8 bf_[NF];
#pragma unroll
        for (int n = 0; n < NF; ++n)
            bf_[n] = *(const short8*)&Bs[(wc * WN + n * 16 + lr16) * 32 + lk];
#pragma unroll
        for (int m = 0; m < 4; ++m)
#pragma unroll
            for (int n = 0; n < NF; ++n)
                acc[m][n] = __builtin_amdgcn_mfma_f32_16x16x32_bf16(af[m], bf_[n], acc[m][n], 0, 0, 0);
        __syncthreads();
    }

    // epilogue: C/D layout col=lane&15, row=(lane>>4)*4+reg
    const int r4 = (lane >> 4) * 4;
#pragma unroll
    for (int m = 0; m < 4; ++m) {
#pragma unroll
        for (int n = 0; n < NF; ++n) {
            const int col = bn + wc * WN + n * 16 + lr16;
            const float bv = bias[col];
#pragma unroll
            for (int j = 0; j < 4; ++j) {
                const int row = bm + wr * 64 + m * 16 + r4 + j;
                store1(C + (size_t)row * N + col, acc[m][n][j] + bv);
            }
        }
    }
}

// ---------------- local attention stitch ----------------
__global__ __launch_bounds__(256) void attn_k(
    const bf16* __restrict__ PQK, const bf16* __restrict__ PV, bf16* __restrict__ Aout)
{
    const int lane = threadIdx.x & 63;
    const int wave = threadIdx.x >> 6;
    const int task = blockIdx.x * 4 + wave;  // 0..32767
    const int h  = task & 7;
    const int bl = task >> 3;
    const int l  = bl & 2047;
    const int d  = c_dil[h];

    const float q = __bfloat162float(PQK[(size_t)bl * 3072 + h * 64 + lane]);

    float logits[5], vvals[5];
#pragma unroll
    for (int kk = 0; kk < 5; ++kk) {
        const int pos = l + (kk - 2) * d;
        const bool ok = (pos >= 0) && (pos < 2048);
        float kv = 0.f, vv = 0.f;
        if (ok) {
            const size_t rb = (size_t)(bl - l + pos);
            kv = __bfloat162float(PQK[rb * 3072 + 512 + (h * 5 + kk) * 64 + lane]);
            vv = __bfloat162float(PV[rb * 2560 + (h * 5 + kk) * 64 + lane]);
        }
        vvals[kk] = vv;
        float lg = q * kv;
#pragma unroll
        for (int s = 32; s; s >>= 1) lg += __shfl_xor(lg, s);
        logits[kk] = lg;  // OOB -> 0, matches reference (zero-padded content, zero bias)
    }

    float mx = logits[0];
#pragma unroll
    for (int kk = 1; kk < 5; ++kk) mx = fmaxf(mx, logits[kk]);
    float e[5], ssum = 0.f;
#pragma unroll
    for (int kk = 0; kk < 5; ++kk) { e[kk] = __expf(logits[kk] - mx); ssum += e[kk]; }
    float acc = 0.f;
#pragma unroll
    for (int kk = 0; kk < 5; ++kk) acc += e[kk] * vvals[kk];
    acc *= 0.125f / ssum;

    Aout[(size_t)bl * 512 + h * 64 + lane] = __float2bfloat16(acc);
}

// ---------------- launch ----------------
extern "C" void kernel_launch(void* const* d_in, const int* in_sizes, int n_in,
                              void* d_out, int out_size, void* d_ws, size_t ws_size,
                              hipStream_t stream)
{
    const float* x   = (const float*)d_in[0];
    const float* q_w = (const float*)d_in[1];
    const float* q_b = (const float*)d_in[2];
    const float* k_w = (const float*)d_in[3];
    const float* k_b = (const float*)d_in[4];
    const float* v_w = (const float*)d_in[5];
    const float* v_b = (const float*)d_in[6];
    const float* o_w = (const float*)d_in[7];
    const float* o_b = (const float*)d_in[8];
    float* out = (float*)d_out;

    const int M = 4096;

    // split path needs 63,975,424 B; plain path 56,635,392 B (proven in round 1)
    const int split = (ws_size >= 63975424ull) ? 1 : 0;
    const int ldx = split ? 1024 : 512;

    char* p = (char*)d_ws;
    bf16* A2  = (bf16*)p;  p += (size_t)M * ldx * 2;
    bf16* Wqk = (bf16*)p;  p += (size_t)3072 * ldx * 2;
    bf16* Wv  = (bf16*)p;  p += (size_t)2560 * 512 * 2;
    bf16* Wo  = (bf16*)p;  p += (size_t)512 * 512 * 2;
    float* bqk = (float*)p; p += 3072 * 4;
    bf16* PQK = (bf16*)p;  p += (size_t)M * 3072 * 2;
    bf16* PV  = (bf16*)p;
    bf16* Aout = A2;  // A2 dead after V-GEMM; reuse for attention output

    dim3 blk(256);
    conv_split<<<dim3(M * 512 / 1024), blk, 0, stream>>>(x, A2, ldx, split);
    conv_split<<<dim3(512 * 512 / 1024), blk, 0, stream>>>(q_w, Wqk, ldx, split);
    conv_split<<<dim3(2560 * 512 / 1024), blk, 0, stream>>>(k_w, Wqk + (size_t)512 * ldx, ldx, split);
    conv_split<<<dim3(2560 * 512 / 1024), blk, 0, stream>>>(v_w, Wv, 512, 0);
    conv_split<<<dim3(512 * 512 / 1024), blk, 0, stream>>>(o_w, Wo, 512, 0);
    pack_bias<<<dim3(12), blk, 0, stream>>>(q_b, k_b, bqk);

    mfma_gemm<128, bf16><<<dim3(3072 / 128, M / 128), blk, 0, stream>>>(
        A2, Wqk, bqk, PQK, M, 3072, ldx, ldx, split ? 3 : 1);
    mfma_gemm<128, bf16><<<dim3(2560 / 128, M / 128), blk, 0, stream>>>(
        A2, Wv, v_b, PV, M, 2560, ldx, 512, 1);
    attn_k<<<dim3(8192), blk, 0, stream>>>(PQK, PV, Aout);
    mfma_gemm<64, float><<<dim3(512 / 64, M / 128), blk, 0, stream>>>(
        Aout, Wo, o_b, out, M, 512, 512, 512, 1);
}

// Round 3
// 112.888 us; speedup vs baseline: 3.4446x; 1.2252x over previous
//
#include <hip/hip_runtime.h>
#include <hip/hip_bf16.h>

using bf16 = __hip_bfloat16;
typedef __attribute__((ext_vector_type(8))) short short8;
typedef __attribute__((ext_vector_type(4))) float f32x4;

__device__ __constant__ int c_dil[8] = {1, 2, 4, 8, 1, 2, 4, 8};

__device__ inline void store1(float* p, float v) { *p = v; }
__device__ inline void store1(bf16* p, float v) { *p = __float2bfloat16(v); }

// async global->LDS, 16 B per lane; LDS dest must be wave-uniform
__device__ inline void gload_lds16(const void* g, void* l) {
    __builtin_amdgcn_global_load_lds(
        (const __attribute__((address_space(1))) unsigned int*)g,
        (__attribute__((address_space(3))) unsigned int*)l, 16, 0, 0);
}

// ---------------- fused convert: f32 -> bf16, modes plain/split/dup + bias pack ----------------
// mode 0: dst row = ld, plain hi
// mode 1: dst row = 1024, [hi | lo]   (x)
// mode 2: dst row = 1024, [hi | hi]   (QK weights, duplicated for the K=1024 exact-x schedule)
__device__ inline void conv_block(const float* __restrict__ src, bf16* __restrict__ dst,
                                  int ld, int mode, int idx) {
    const float4 v = *reinterpret_cast<const float4*>(src + idx);
    const int r = idx >> 9, c = idx & 511;
    bf16* d = dst + (size_t)r * ld + c;
    const float vv[4] = {v.x, v.y, v.z, v.w};
#pragma unroll
    for (int j = 0; j < 4; ++j) {
        const bf16 h = __float2bfloat16(vv[j]);
        d[j] = h;
        if (mode == 1) d[512 + j] = __float2bfloat16(vv[j] - __bfloat162float(h));
        else if (mode == 2) d[512 + j] = h;
    }
}

__global__ __launch_bounds__(256) void conv_all(
    const float* __restrict__ x,  const float* __restrict__ qw, const float* __restrict__ kw,
    const float* __restrict__ vw, const float* __restrict__ ow,
    const float* __restrict__ qb, const float* __restrict__ kb,
    bf16* A2, bf16* Wqk, bf16* Wv, bf16* Wo, float* bqk)
{
    const int b = blockIdx.x, t = threadIdx.x;
    if (b < 2048)       conv_block(x,  A2,                       1024, 1, (b * 256 + t) * 4);
    else if (b < 2304)  conv_block(qw, Wqk,                      1024, 2, ((b - 2048) * 256 + t) * 4);
    else if (b < 3584)  conv_block(kw, Wqk + (size_t)512 * 1024, 1024, 2, ((b - 2304) * 256 + t) * 4);
    else if (b < 4864)  conv_block(vw, Wv,                        512, 0, ((b - 3584) * 256 + t) * 4);
    else if (b < 5120)  conv_block(ow, Wo,                        512, 0, ((b - 4864) * 256 + t) * 4);
    else { const int i = (b - 5120) * 256 + t; bqk[i] = (i < 512) ? qb[i] : kb[i - 512]; }
}

// ---------------- MFMA GEMM, 128x128 tile, BK=32, 4 waves (2x2), dual-target ----------------
// Block col-tile bx < nx0 -> target 0 (W0/b0/C0, nt0 K-steps), else target 1.
// A rows are lda bf16; K iterated kk = s*32, s < nsteps (target 1 may use fewer steps,
// reading only the hi half of A).
template <typename TC>
__global__ __launch_bounds__(256) void gemm128(
    const bf16* __restrict__ A, int lda,
    const bf16* __restrict__ W0, int ldw0, const float* __restrict__ b0,
    TC* __restrict__ C0, int ldc0, int nt0, int nx0,
    const bf16* __restrict__ W1, int ldw1, const float* __restrict__ b1,
    bf16* __restrict__ C1, int ldc1, int nt1)
{
    __shared__ short As[128 * 32];   // [m][k], 64 B rows
    __shared__ short Bs[128 * 32];   // [n][k]

    const int tid = threadIdx.x, wid = tid >> 6, lane = tid & 63;
    const int bm = blockIdx.y * 128;
    const bool t0 = (int)blockIdx.x < nx0;
    const int bn = (t0 ? blockIdx.x : blockIdx.x - nx0) * 128;
    const bf16* W      = t0 ? W0 : W1;
    const int   ldw    = t0 ? ldw0 : ldw1;
    const float* bias  = t0 ? b0 : b1;
    const int   nsteps = t0 ? nt0 : nt1;

    const int srow = lane >> 2;           // 0..15
    const int scol = (lane & 3) * 16;     // 0,16,32,48 bytes

    // per-thread staging source pointers (advance +64 B per K-step)
    const char* pA0 = (const char*)A + (size_t)(bm + wid * 16 + srow) * lda * 2 + scol;
    const char* pA1 = (const char*)A + (size_t)(bm + (wid + 4) * 16 + srow) * lda * 2 + scol;
    const char* pB0 = (const char*)W + (size_t)(bn + wid * 16 + srow) * ldw * 2 + scol;
    const char* pB1 = (const char*)W + (size_t)(bn + (wid + 4) * 16 + srow) * ldw * 2 + scol;
    char* dA0 = (char*)As + wid * 1024;
    char* dA1 = (char*)As + (wid + 4) * 1024;
    char* dB0 = (char*)Bs + wid * 1024;
    char* dB1 = (char*)Bs + (wid + 4) * 1024;

    f32x4 acc[4][4];
#pragma unroll
    for (int i = 0; i < 4; ++i)
#pragma unroll
        for (int j = 0; j < 4; ++j) acc[i][j] = f32x4{0.f, 0.f, 0.f, 0.f};

    const int lr16 = lane & 15;
    const int lk   = (lane >> 4) * 8;
    const int wr = wid >> 1, wc = wid & 1;

    for (int s = 0; s < nsteps; ++s) {
        gload_lds16(pA0, dA0);
        gload_lds16(pA1, dA1);
        gload_lds16(pB0, dB0);
        gload_lds16(pB1, dB1);
        pA0 += 64; pA1 += 64; pB0 += 64; pB1 += 64;
        __syncthreads();   // drains vmcnt+lgkmcnt before barrier

        short8 af[4], bw[4];
#pragma unroll
        for (int m = 0; m < 4; ++m)
            af[m] = *(const short8*)&As[(wr * 64 + m * 16 + lr16) * 32 + lk];
#pragma unroll
        for (int n = 0; n < 4; ++n)
            bw[n] = *(const short8*)&Bs[(wc * 64 + n * 16 + lr16) * 32 + lk];
#pragma unroll
        for (int m = 0; m < 4; ++m)
#pragma unroll
            for (int n = 0; n < 4; ++n)
                acc[m][n] = __builtin_amdgcn_mfma_f32_16x16x32_bf16(af[m], bw[n], acc[m][n], 0, 0, 0);
        __syncthreads();
    }

    // epilogue: C/D layout col=lane&15, row=(lane>>4)*4+reg
    const int r4 = (lane >> 4) * 4;
#pragma unroll
    for (int m = 0; m < 4; ++m) {
#pragma unroll
        for (int n = 0; n < 4; ++n) {
            const int col = bn + wc * 64 + n * 16 + lr16;
            const float bv = bias[col];
#pragma unroll
            for (int j = 0; j < 4; ++j) {
                const int row = bm + wr * 64 + m * 16 + r4 + j;
                const float v = acc[m][n][j] + bv;
                if (t0) store1(C0 + (size_t)row * ldc0 + col, v);
                else    store1(C1 + (size_t)row * ldc1 + col, v);
            }
        }
    }
}

// ---------------- local attention stitch ----------------
__global__ __launch_bounds__(256) void attn_k(
    const bf16* __restrict__ PQK, const bf16* __restrict__ PV, bf16* __restrict__ Aout)
{
    const int lane = threadIdx.x & 63;
    const int wave = threadIdx.x >> 6;
    const int task = blockIdx.x * 4 + wave;  // 0..32767
    const int h  = task & 7;
    const int bl = task >> 3;
    const int l  = bl & 2047;
    const int d  = c_dil[h];

    const float q = __bfloat162float(PQK[(size_t)bl * 3072 + h * 64 + lane]);

    float logits[5], vvals[5];
#pragma unroll
    for (int kk = 0; kk < 5; ++kk) {
        const int pos = l + (kk - 2) * d;
        const bool ok = (pos >= 0) && (pos < 2048);
        float kv = 0.f, vv = 0.f;
        if (ok) {
            const size_t rb = (size_t)(bl - l + pos);
            kv = __bfloat162float(PQK[rb * 3072 + 512 + (h * 5 + kk) * 64 + lane]);
            vv = __bfloat162float(PV[rb * 2560 + (h * 5 + kk) * 64 + lane]);
        }
        vvals[kk] = vv;
        float lg = q * kv;
#pragma unroll
        for (int s = 32; s; s >>= 1) lg += __shfl_xor(lg, s);
        logits[kk] = lg;  // OOB -> 0, matches reference (zero-padded content, zero bias)
    }

    float mx = logits[0];
#pragma unroll
    for (int kk = 1; kk < 5; ++kk) mx = fmaxf(mx, logits[kk]);
    float e[5], ssum = 0.f;
#pragma unroll
    for (int kk = 0; kk < 5; ++kk) { e[kk] = __expf(logits[kk] - mx); ssum += e[kk]; }
    float acc = 0.f;
#pragma unroll
    for (int kk = 0; kk < 5; ++kk) acc += e[kk] * vvals[kk];
    acc *= 0.125f / ssum;

    Aout[(size_t)bl * 512 + h * 64 + lane] = __float2bfloat16(acc);
}

// ---------------- launch ----------------
extern "C" void kernel_launch(void* const* d_in, const int* in_sizes, int n_in,
                              void* d_out, int out_size, void* d_ws, size_t ws_size,
                              hipStream_t stream)
{
    const float* x   = (const float*)d_in[0];
    const float* q_w = (const float*)d_in[1];
    const float* q_b = (const float*)d_in[2];
    const float* k_w = (const float*)d_in[3];
    const float* k_b = (const float*)d_in[4];
    const float* v_w = (const float*)d_in[5];
    const float* v_b = (const float*)d_in[6];
    const float* o_w = (const float*)d_in[7];
    const float* o_b = (const float*)d_in[8];
    float* out = (float*)d_out;

    const int M = 4096;

    // workspace: 8 + 6 + 2.5 + 0.5 + 0.012 + 24 + 20 = 61.0 MB (round-2 used 64 MB OK)
    char* p = (char*)d_ws;
    bf16* A2  = (bf16*)p;  p += (size_t)M * 1024 * 2;       // [x_hi | x_lo]
    bf16* Wqk = (bf16*)p;  p += (size_t)3072 * 1024 * 2;    // [w_hi | w_hi] (q rows 0-511, k rows 512-3071)
    bf16* Wv  = (bf16*)p;  p += (size_t)2560 * 512 * 2;
    bf16* Wo  = (bf16*)p;  p += (size_t)512 * 512 * 2;
    float* bqk = (float*)p; p += 3072 * 4;
    bf16* PQK = (bf16*)p;  p += (size_t)M * 3072 * 2;
    bf16* PV  = (bf16*)p;
    bf16* Aout = A2;  // A2 dead after the QKV GEMM; reuse for attention output

    dim3 blk(256);
    conv_all<<<dim3(5132), blk, 0, stream>>>(x, q_w, k_w, v_w, o_w, q_b, k_b,
                                             A2, Wqk, Wv, Wo, bqk);
    // fused QKV: col-tiles 0-23 -> PQK (K=1024 exact-x schedule), 24-43 -> PV (K=512, hi half)
    gemm128<bf16><<<dim3(44, M / 128), blk, 0, stream>>>(
        A2, 1024,
        Wqk, 1024, bqk, PQK, 3072, 32, 24,
        Wv,  512,  v_b, PV,  2560, 16);
    attn_k<<<dim3(8192), blk, 0, stream>>>(PQK, PV, Aout);
    gemm128<float><<<dim3(4, M / 128), blk, 0, stream>>>(
        Aout, 512,
        Wo, 512, o_b, out, 512, 16, 4,
        Wo, 512, o_b, PQK, 512, 16);  // target-1 args unused (nx0 covers grid)
}

// Round 4
// 100.563 us; speedup vs baseline: 3.8667x; 1.1226x over previous
//
#include <hip/hip_runtime.h>
#include <hip/hip_bf16.h>

using bf16 = __hip_bfloat16;
typedef __attribute__((ext_vector_type(8))) short short8;
typedef __attribute__((ext_vector_type(4))) float f32x4;

__device__ __constant__ int c_dil[8] = {1, 2, 4, 8, 1, 2, 4, 8};

__device__ inline void store1(float* p, float v) { *p = v; }
__device__ inline void store1(bf16* p, float v) { *p = __float2bfloat16(v); }

// async global->LDS, 16 B per lane; LDS dest must be wave-uniform base + lane*16
__device__ inline void gload_lds16(const void* g, void* l) {
    __builtin_amdgcn_global_load_lds(
        (const __attribute__((address_space(1))) unsigned int*)g,
        (__attribute__((address_space(3))) unsigned int*)l, 16, 0, 0);
}

// manual RNE f32->bf16 (bit-identical to HW for normal values)
__device__ inline unsigned short f2bf(float f) {
    const unsigned u = __float_as_uint(f);
    return (unsigned short)((u + 0x7fffu + ((u >> 16) & 1u)) >> 16);
}
__device__ inline float bf2f(unsigned short h) { return __uint_as_float(((unsigned)h) << 16); }

// ---------------- fused convert: f32 -> bf16 ----------------
// mode 0: row = ld, plain;  mode 1: row = 1024, [hi|lo] (x);  mode 2: row = 1024, [hi|hi] (QK w)
__device__ inline void conv_block(const float* __restrict__ src, bf16* __restrict__ dst,
                                  int ld, int mode, int idx) {
    const float4 v = *reinterpret_cast<const float4*>(src + idx);
    const int r = idx >> 9, c = idx & 511;
    bf16* d = dst + (size_t)r * ld + c;
    const float vv[4] = {v.x, v.y, v.z, v.w};
    ushort4 hi, lo;
    unsigned short* hp = &hi.x; unsigned short* lp = &lo.x;
#pragma unroll
    for (int j = 0; j < 4; ++j) {
        hp[j] = f2bf(vv[j]);
        lp[j] = f2bf(vv[j] - bf2f(hp[j]));
    }
    *reinterpret_cast<ushort4*>(d) = hi;
    if (mode == 1) *reinterpret_cast<ushort4*>(d + 512) = lo;
    else if (mode == 2) *reinterpret_cast<ushort4*>(d + 512) = hi;
}

__global__ __launch_bounds__(256) void conv_all(
    const float* __restrict__ x,  const float* __restrict__ qw, const float* __restrict__ kw,
    const float* __restrict__ vw, const float* __restrict__ ow,
    const float* __restrict__ qb, const float* __restrict__ kb,
    bf16* A2, bf16* Wqk, bf16* Wv, bf16* Wo, float* bqk)
{
    const int b = blockIdx.x, t = threadIdx.x;
    if (b < 2048)       conv_block(x,  A2,                       1024, 1, (b * 256 + t) * 4);
    else if (b < 2304)  conv_block(qw, Wqk,                      1024, 2, ((b - 2048) * 256 + t) * 4);
    else if (b < 3584)  conv_block(kw, Wqk + (size_t)512 * 1024, 1024, 2, ((b - 2304) * 256 + t) * 4);
    else if (b < 4864)  conv_block(vw, Wv,                        512, 0, ((b - 3584) * 256 + t) * 4);
    else if (b < 5120)  conv_block(ow, Wo,                        512, 0, ((b - 4864) * 256 + t) * 4);
    else { const int i = (b - 5120) * 256 + t; bqk[i] = (i < 512) ? qb[i] : kb[i - 512]; }
}

// ---------------- MFMA GEMM, 128 x BN tile, BK=32, 4 waves, dbuf + 1 barrier/step ----------
// LDS layout per 16-row chunk (1024 B): slot s holds global (row = s>>2,
// word w_data = (s&3) ^ ((s>>3)&3)) -- source pre-swizzle so strided reads are 2-way max.
// Dual-target: 1D grid, XCD-swizzled; col-tile bx < nx0 -> target 0, else target 1 (fewer K-steps,
// reads only the hi half of A).
template <int BN, typename TC>
__global__ __launch_bounds__(256) void gemm128(
    const bf16* __restrict__ A, int lda, int ncols,
    const bf16* __restrict__ W0, int ldw0, const float* __restrict__ b0,
    TC* __restrict__ C0, int ldc0, int nt0, int nx0,
    const bf16* __restrict__ W1, int ldw1, const float* __restrict__ b1,
    bf16* __restrict__ C1, int ldc1, int nt1)
{
    constexpr int NF = BN / 32;                 // per-wave N fragments (wave covers NF*16 cols)
    __shared__ short As[2][128 * 32];
    __shared__ short Bs[2][BN * 32];

    const int tid = threadIdx.x, wid = tid >> 6, lane = tid & 63;

    // bijective XCD swizzle (gridDim.x % 8 == 0)
    const int q8 = (int)gridDim.x >> 3;
    const int bid = ((int)blockIdx.x & 7) * q8 + ((int)blockIdx.x >> 3);
    const int bx = bid % ncols, by = bid / ncols;

    const int bm = by * 128;
    const bool t0 = bx < nx0;
    const int bn = (t0 ? bx : bx - nx0) * BN;
    const bf16* W      = t0 ? W0 : W1;
    const int   ldw    = t0 ? ldw0 : ldw1;
    const float* bias  = t0 ? b0 : b1;
    const int   nsteps = t0 ? nt0 : nt1;

    // staging source pointers (global, pre-swizzled word within each 64 B row-window)
    const int srow = lane >> 2;
    const int ssw  = (((lane & 3) ^ ((lane >> 3) & 3)) << 4);   // swizzled word * 16 B
    const char* pA0 = (const char*)A + (size_t)(bm + wid * 16 + srow) * lda * 2 + ssw;
    const char* pA1 = pA0 + (size_t)64 * lda * 2;
    const char* pB0 = (const char*)W + (size_t)(bn + wid * 16 + srow) * ldw * 2 + ssw;
    const char* pB1 = pB0 + (size_t)64 * ldw * 2;   // used only when BN == 128

    f32x4 acc[4][NF];
#pragma unroll
    for (int i = 0; i < 4; ++i)
#pragma unroll
        for (int j = 0; j < NF; ++j) acc[i][j] = f32x4{0.f, 0.f, 0.f, 0.f};

    // read offsets: fragment (chunk, row lr16, word lane>>4), XOR-unswizzled (per-thread const)
    const int lr16 = lane & 15;
    const int wsw8 = (((lane >> 4) ^ ((lr16 >> 1) & 3)) << 3);  // swizzled word * 8 shorts
    const int wr = wid >> 1, wc = wid & 1;
    int offA[4], offB[NF];
#pragma unroll
    for (int m = 0; m < 4; ++m) offA[m] = (wr * 4 + m) * 512 + lr16 * 32 + wsw8;
#pragma unroll
    for (int n = 0; n < NF; ++n) offB[n] = (wc * NF + n) * 512 + lr16 * 32 + wsw8;

    auto stage = [&](int buf) {
        gload_lds16(pA0, (char*)As[buf] + wid * 1024);
        gload_lds16(pA1, (char*)As[buf] + (wid + 4) * 1024);
        gload_lds16(pB0, (char*)Bs[buf] + wid * 1024);
        if constexpr (BN == 128) gload_lds16(pB1, (char*)Bs[buf] + (wid + 4) * 1024);
        pA0 += 64; pA1 += 64; pB0 += 64;
        if constexpr (BN == 128) pB1 += 64;
    };

    stage(0);
    __syncthreads();   // drain prologue loads

    for (int s = 0; s < nsteps; ++s) {
        const int buf = s & 1;
        if (s + 1 < nsteps) stage(buf ^ 1);   // loads fly under this step's compute

        short8 af[4], bw[NF];
#pragma unroll
        for (int m = 0; m < 4; ++m)
            af[m] = *(const short8*)&As[buf][offA[m]];
#pragma unroll
        for (int n = 0; n < NF; ++n)
            bw[n] = *(const short8*)&Bs[buf][offB[n]];
#pragma unroll
        for (int m = 0; m < 4; ++m)
#pragma unroll
            for (int n = 0; n < NF; ++n)
                acc[m][n] = __builtin_amdgcn_mfma_f32_16x16x32_bf16(af[m], bw[n], acc[m][n], 0, 0, 0);

        __syncthreads();  // one barrier/step: drains next-tile vmcnt + this-tile lgkmcnt
    }

    // epilogue: C/D layout col=lane&15, row=(lane>>4)*4+reg
    const int r4 = (lane >> 4) * 4;
#pragma unroll
    for (int m = 0; m < 4; ++m) {
#pragma unroll
        for (int n = 0; n < NF; ++n) {
            const int col = bn + wc * (NF * 16) + n * 16 + lr16;
            const float bv = bias[col];
#pragma unroll
            for (int j = 0; j < 4; ++j) {
                const int row = bm + wr * 64 + m * 16 + r4 + j;
                const float v = acc[m][n][j] + bv;
                if (t0) store1(C0 + (size_t)row * ldc0 + col, v);
                else    store1(C1 + (size_t)row * ldc1 + col, v);
            }
        }
    }
}

// ---------------- local attention stitch ----------------
__global__ __launch_bounds__(256) void attn_k(
    const bf16* __restrict__ PQK, const bf16* __restrict__ PV, bf16* __restrict__ Aout)
{
    const int lane = threadIdx.x & 63;
    const int wave = threadIdx.x >> 6;
    const int task = blockIdx.x * 4 + wave;  // 0..32767
    const int h  = task & 7;
    const int bl = task >> 3;
    const int l  = bl & 2047;
    const int d  = c_dil[h];

    const float q = __bfloat162float(PQK[(size_t)bl * 3072 + h * 64 + lane]);

    float logits[5], vvals[5];
#pragma unroll
    for (int kk = 0; kk < 5; ++kk) {
        const int pos = l + (kk - 2) * d;
        const bool ok = (pos >= 0) && (pos < 2048);
        float kv = 0.f, vv = 0.f;
        if (ok) {
            const size_t rb = (size_t)(bl - l + pos);
            kv = __bfloat162float(PQK[rb * 3072 + 512 + (h * 5 + kk) * 64 + lane]);
            vv = __bfloat162float(PV[rb * 2560 + (h * 5 + kk) * 64 + lane]);
        }
        vvals[kk] = vv;
        float lg = q * kv;
#pragma unroll
        for (int s = 32; s; s >>= 1) lg += __shfl_xor(lg, s);
        logits[kk] = lg;  // OOB -> 0, matches reference (zero-padded content, zero bias)
    }

    float mx = logits[0];
#pragma unroll
    for (int kk = 1; kk < 5; ++kk) mx = fmaxf(mx, logits[kk]);
    float e[5], ssum = 0.f;
#pragma unroll
    for (int kk = 0; kk < 5; ++kk) { e[kk] = __expf(logits[kk] - mx); ssum += e[kk]; }
    float acc = 0.f;
#pragma unroll
    for (int kk = 0; kk < 5; ++kk) acc += e[kk] * vvals[kk];
    acc *= 0.125f / ssum;

    Aout[(size_t)bl * 512 + h * 64 + lane] = __float2bfloat16(acc);
}

// ---------------- launch ----------------
extern "C" void kernel_launch(void* const* d_in, const int* in_sizes, int n_in,
                              void* d_out, int out_size, void* d_ws, size_t ws_size,
                              hipStream_t stream)
{
    const float* x   = (const float*)d_in[0];
    const float* q_w = (const float*)d_in[1];
    const float* q_b = (const float*)d_in[2];
    const float* k_w = (const float*)d_in[3];
    const float* k_b = (const float*)d_in[4];
    const float* v_w = (const float*)d_in[5];
    const float* v_b = (const float*)d_in[6];
    const float* o_w = (const float*)d_in[7];
    const float* o_b = (const float*)d_in[8];
    float* out = (float*)d_out;

    const int M = 4096;

    // workspace: 8 + 6 + 2.5 + 0.5 + 0.012 + 24 + 20 = 61.0 MB
    char* p = (char*)d_ws;
    bf16* A2  = (bf16*)p;  p += (size_t)M * 1024 * 2;       // [x_hi | x_lo]
    bf16* Wqk = (bf16*)p;  p += (size_t)3072 * 1024 * 2;    // [w_hi | w_hi]
    bf16* Wv  = (bf16*)p;  p += (size_t)2560 * 512 * 2;
    bf16* Wo  = (bf16*)p;  p += (size_t)512 * 512 * 2;
    float* bqk = (float*)p; p += 3072 * 4;
    bf16* PQK = (bf16*)p;  p += (size_t)M * 3072 * 2;
    bf16* PV  = (bf16*)p;
    bf16* Aout = A2;  // A2 dead after the QKV GEMM; reuse for attention output

    dim3 blk(256);
    conv_all<<<dim3(5132), blk, 0, stream>>>(x, q_w, k_w, v_w, o_w, q_b, k_b,
                                             A2, Wqk, Wv, Wo, bqk);
    // fused QKV: col-tiles 0-23 -> PQK (K=1024 exact-x schedule), 24-43 -> PV (K=512, hi half)
    gemm128<128, bf16><<<dim3(44 * 32), blk, 0, stream>>>(
        A2, 1024, 44,
        Wqk, 1024, bqk, PQK, 3072, 32, 24,
        Wv,  512,  v_b, PV,  2560, 16);
    attn_k<<<dim3(8192), blk, 0, stream>>>(PQK, PV, Aout);
    gemm128<64, float><<<dim3(8 * 32), blk, 0, stream>>>(
        Aout, 512, 8,
        Wo, 512, o_b, out, 512, 16, 8,
        Wo, 512, o_b, PQK, 512, 16);  // target-1 args unused (nx0 covers grid)
}

// Round 5
// 98.298 us; speedup vs baseline: 3.9558x; 1.0230x over previous
//
#include <hip/hip_runtime.h>
#include <hip/hip_bf16.h>

using bf16 = __hip_bfloat16;
typedef __attribute__((ext_vector_type(8))) short short8;
typedef __attribute__((ext_vector_type(4))) float f32x4;

__device__ __constant__ int c_dil[8] = {1, 2, 4, 8, 1, 2, 4, 8};

__device__ inline void store1(float* p, float v) { *p = v; }
__device__ inline void store1(bf16* p, float v) { *p = __float2bfloat16(v); }

// async global->LDS, 16 B per lane; LDS dest must be wave-uniform base + lane*16
__device__ inline void gload_lds16(const void* g, void* l) {
    __builtin_amdgcn_global_load_lds(
        (const __attribute__((address_space(1))) unsigned int*)g,
        (__attribute__((address_space(3))) unsigned int*)l, 16, 0, 0);
}

template <int N> __device__ inline void vwait() {
    asm volatile("s_waitcnt vmcnt(%0)" :: "n"(N) : "memory");
}

// manual RNE f32->bf16
__device__ inline unsigned short f2bf(float f) {
    const unsigned u = __float_as_uint(f);
    return (unsigned short)((u + 0x7fffu + ((u >> 16) & 1u)) >> 16);
}
__device__ inline float bf2f(unsigned short h) { return __uint_as_float(((unsigned)h) << 16); }

// ---------------- fused convert: f32 -> bf16 ----------------
// mode 0: row = ld, plain;  mode 1: row = 1024, [hi|lo] (x);  mode 2: row = 1024, [hi|hi] (QK w)
__device__ inline void conv_block(const float* __restrict__ src, bf16* __restrict__ dst,
                                  int ld, int mode, int idx) {
    const float4 v = *reinterpret_cast<const float4*>(src + idx);
    const int r = idx >> 9, c = idx & 511;
    bf16* d = dst + (size_t)r * ld + c;
    const float vv[4] = {v.x, v.y, v.z, v.w};
    ushort4 hi, lo;
    unsigned short* hp = &hi.x; unsigned short* lp = &lo.x;
#pragma unroll
    for (int j = 0; j < 4; ++j) {
        hp[j] = f2bf(vv[j]);
        lp[j] = f2bf(vv[j] - bf2f(hp[j]));
    }
    *reinterpret_cast<ushort4*>(d) = hi;
    if (mode == 1) *reinterpret_cast<ushort4*>(d + 512) = lo;
    else if (mode == 2) *reinterpret_cast<ushort4*>(d + 512) = hi;
}

__global__ __launch_bounds__(256) void conv_all(
    const float* __restrict__ x,  const float* __restrict__ qw, const float* __restrict__ kw,
    const float* __restrict__ vw, const float* __restrict__ ow,
    const float* __restrict__ qb, const float* __restrict__ kb,
    bf16* A2, bf16* Wqk, bf16* Wv, bf16* Wo, float* bqk)
{
    const int b = blockIdx.x, t = threadIdx.x;
    if (b < 2048)       conv_block(x,  A2,                       1024, 1, (b * 256 + t) * 4);
    else if (b < 2304)  conv_block(qw, Wqk,                      1024, 2, ((b - 2048) * 256 + t) * 4);
    else if (b < 3584)  conv_block(kw, Wqk + (size_t)512 * 1024, 1024, 2, ((b - 2304) * 256 + t) * 4);
    else if (b < 4864)  conv_block(vw, Wv,                        512, 0, ((b - 3584) * 256 + t) * 4);
    else if (b < 5120)  conv_block(ow, Wo,                        512, 0, ((b - 4864) * 256 + t) * 4);
    else { const int i = (b - 5120) * 256 + t; bqk[i] = (i < 512) ? qb[i] : kb[i - 512]; }
}

// ---------------- MFMA GEMM, 128 x BN tile, BK=32, 4 waves ----------------
// 3-buffer LDS pipeline, counted vmcnt (tiles s+1,s+2 stay in flight across barriers),
// raw s_barrier (no drain). Source-swizzled staging keeps LDS reads 2-way max (free).
// Grid: 1D, XCD-chunked (xcd = blockIdx&7): per XCD cw-col x rpx-row chunks for L2 locality.
// Dual-target: col-tile bx < nx0 -> target 0, else target 1 (fewer K-steps, hi half of A only).
template <int BN, typename TC>
__global__ __launch_bounds__(256) void gemm128(
    const bf16* __restrict__ A, int lda, int cw, int rpx,
    const bf16* __restrict__ W0, int ldw0, const float* __restrict__ b0,
    TC* __restrict__ C0, int ldc0, int nt0, int nx0,
    const bf16* __restrict__ W1, int ldw1, const float* __restrict__ b1,
    bf16* __restrict__ C1, int ldc1, int nt1)
{
    constexpr int NF = BN / 32;                  // per-wave N fragments
    constexpr int NLOAD = (BN == 128) ? 4 : 3;   // gload_lds per wave per stage
    __shared__ short As[3][128 * 32];
    __shared__ short Bs[3][BN * 32];

    const int tid = threadIdx.x, wid = tid >> 6, lane = tid & 63;

    // XCD-chunked mapping
    const int xcd = (int)blockIdx.x & 7;
    const int i   = (int)blockIdx.x >> 3;
    const int grp = rpx * cw;
    const int cc = i / grp, w2 = i % grp;
    const int rr = w2 / cw, c = w2 % cw;
    const int bx = cc * cw + c;
    const int by = xcd * rpx + rr;

    const int bm = by * 128;
    const bool t0 = bx < nx0;
    const int bn = (t0 ? bx : bx - nx0) * BN;
    const bf16* W      = t0 ? W0 : W1;
    const int   ldw    = t0 ? ldw0 : ldw1;
    const float* bias  = t0 ? b0 : b1;
    const int   nsteps = t0 ? nt0 : nt1;

    // staging source pointers (pre-swizzled word within each 64 B row-window)
    const int srow = lane >> 2;
    const int ssw  = (((lane & 3) ^ ((lane >> 3) & 3)) << 4);
    const char* pA0 = (const char*)A + (size_t)(bm + wid * 16 + srow) * lda * 2 + ssw;
    const char* pA1 = pA0 + (size_t)64 * lda * 2;
    const char* pB0 = (const char*)W + (size_t)(bn + wid * 16 + srow) * ldw * 2 + ssw;
    const char* pB1 = pB0 + (size_t)64 * ldw * 2;   // BN==128 only

    f32x4 acc[4][NF];
#pragma unroll
    for (int m = 0; m < 4; ++m)
#pragma unroll
        for (int n = 0; n < NF; ++n) acc[m][n] = f32x4{0.f, 0.f, 0.f, 0.f};

    // read offsets (XOR-unswizzled, per-thread constant)
    const int lr16 = lane & 15;
    const int wsw8 = (((lane >> 4) ^ ((lr16 >> 1) & 3)) << 3);
    const int wr = wid >> 1, wc = wid & 1;
    int offA[4], offB[NF];
#pragma unroll
    for (int m = 0; m < 4; ++m) offA[m] = (wr * 4 + m) * 512 + lr16 * 32 + wsw8;
#pragma unroll
    for (int n = 0; n < NF; ++n) offB[n] = (wc * NF + n) * 512 + lr16 * 32 + wsw8;

    auto stage = [&](int buf) {
        gload_lds16(pA0, (char*)As[buf] + wid * 1024);
        gload_lds16(pA1, (char*)As[buf] + (wid + 4) * 1024);
        gload_lds16(pB0, (char*)Bs[buf] + wid * 1024);
        if constexpr (BN == 128) gload_lds16(pB1, (char*)Bs[buf] + (wid + 4) * 1024);
        pA0 += 64; pA1 += 64; pB0 += 64;
        if constexpr (BN == 128) pB1 += 64;
    };

    stage(0);
    stage(1);

    int cur = 0;          // buffer holding tile s
    for (int s = 0; s < nsteps; ++s) {
        // issue tile s+2 into the buffer freed at step s-1; counted waits keep
        // tiles s+1 (and s+2) in flight across the barrier (T4).
        if (s + 2 < nsteps) {
            stage(cur == 0 ? 2 : cur - 1);
            vwait<2 * NLOAD>();
        } else if (s + 1 < nsteps) {
            vwait<NLOAD>();
        } else {
            vwait<0>();
        }
        __builtin_amdgcn_s_barrier();          // all waves' tile-s loads landed
        __builtin_amdgcn_sched_barrier(0);

        short8 af[4], bw[NF];
#pragma unroll
        for (int m = 0; m < 4; ++m)
            af[m] = *(const short8*)&As[cur][offA[m]];
#pragma unroll
        for (int n = 0; n < NF; ++n)
            bw[n] = *(const short8*)&Bs[cur][offB[n]];
#pragma unroll
        for (int m = 0; m < 4; ++m)
#pragma unroll
            for (int n = 0; n < NF; ++n)
                acc[m][n] = __builtin_amdgcn_mfma_f32_16x16x32_bf16(af[m], bw[n], acc[m][n], 0, 0, 0);

        __builtin_amdgcn_s_barrier();          // reads of buf `cur` done -> safe to overwrite next iter
        __builtin_amdgcn_sched_barrier(0);
        cur = (cur == 2) ? 0 : cur + 1;
    }

    // epilogue: C/D layout col=lane&15, row=(lane>>4)*4+reg
    const int r4 = (lane >> 4) * 4;
#pragma unroll
    for (int m = 0; m < 4; ++m) {
#pragma unroll
        for (int n = 0; n < NF; ++n) {
            const int col = bn + wc * (NF * 16) + n * 16 + lr16;
            const float bv = bias[col];
#pragma unroll
            for (int j = 0; j < 4; ++j) {
                const int row = bm + wr * 64 + m * 16 + r4 + j;
                const float v = acc[m][n][j] + bv;
                if (t0) store1(C0 + (size_t)row * ldc0 + col, v);
                else    store1(C1 + (size_t)row * ldc1 + col, v);
            }
        }
    }
}

// ---------------- local attention stitch ----------------
__global__ __launch_bounds__(256) void attn_k(
    const bf16* __restrict__ PQK, const bf16* __restrict__ PV, bf16* __restrict__ Aout)
{
    const int lane = threadIdx.x & 63;
    const int wave = threadIdx.x >> 6;
    const int task = blockIdx.x * 4 + wave;  // 0..32767
    const int h  = task & 7;
    const int bl = task >> 3;
    const int l  = bl & 2047;
    const int d  = c_dil[h];

    const float q = __bfloat162float(PQK[(size_t)bl * 3072 + h * 64 + lane]);

    float logits[5], vvals[5];
#pragma unroll
    for (int kk = 0; kk < 5; ++kk) {
        const int pos = l + (kk - 2) * d;
        const bool ok = (pos >= 0) && (pos < 2048);
        float kv = 0.f, vv = 0.f;
        if (ok) {
            const size_t rb = (size_t)(bl - l + pos);
            kv = __bfloat162float(PQK[rb * 3072 + 512 + (h * 5 + kk) * 64 + lane]);
            vv = __bfloat162float(PV[rb * 2560 + (h * 5 + kk) * 64 + lane]);
        }
        vvals[kk] = vv;
        float lg = q * kv;
#pragma unroll
        for (int s = 32; s; s >>= 1) lg += __shfl_xor(lg, s);
        logits[kk] = lg;  // OOB -> 0, matches reference (zero-padded content, zero bias)
    }

    float mx = logits[0];
#pragma unroll
    for (int kk = 1; kk < 5; ++kk) mx = fmaxf(mx, logits[kk]);
    float e[5], ssum = 0.f;
#pragma unroll
    for (int kk = 0; kk < 5; ++kk) { e[kk] = __expf(logits[kk] - mx); ssum += e[kk]; }
    float acc = 0.f;
#pragma unroll
    for (int kk = 0; kk < 5; ++kk) acc += e[kk] * vvals[kk];
    acc *= 0.125f / ssum;

    Aout[(size_t)bl * 512 + h * 64 + lane] = __float2bfloat16(acc);
}

// ---------------- launch ----------------
extern "C" void kernel_launch(void* const* d_in, const int* in_sizes, int n_in,
                              void* d_out, int out_size, void* d_ws, size_t ws_size,
                              hipStream_t stream)
{
    const float* x   = (const float*)d_in[0];
    const float* q_w = (const float*)d_in[1];
    const float* q_b = (const float*)d_in[2];
    const float* k_w = (const float*)d_in[3];
    const float* k_b = (const float*)d_in[4];
    const float* v_w = (const float*)d_in[5];
    const float* v_b = (const float*)d_in[6];
    const float* o_w = (const float*)d_in[7];
    const float* o_b = (const float*)d_in[8];
    float* out = (float*)d_out;

    const int M = 4096;

    // workspace: 8 + 6 + 2.5 + 0.5 + 0.012 + 24 + 20 = 61.0 MB
    char* p = (char*)d_ws;
    bf16* A2  = (bf16*)p;  p += (size_t)M * 1024 * 2;       // [x_hi | x_lo]
    bf16* Wqk = (bf16*)p;  p += (size_t)3072 * 1024 * 2;    // [w_hi | w_hi]
    bf16* Wv  = (bf16*)p;  p += (size_t)2560 * 512 * 2;
    bf16* Wo  = (bf16*)p;  p += (size_t)512 * 512 * 2;
    float* bqk = (float*)p; p += 3072 * 4;
    bf16* PQK = (bf16*)p;  p += (size_t)M * 3072 * 2;
    bf16* PV  = (bf16*)p;
    bf16* Aout = A2;  // A2 dead after the QKV GEMM; reuse for attention output

    dim3 blk(256);
    conv_all<<<dim3(5132), blk, 0, stream>>>(x, q_w, k_w, v_w, o_w, q_b, k_b,
                                             A2, Wqk, Wv, Wo, bqk);
    // fused QKV: col-tiles 0-23 -> PQK (K=1024 exact-x schedule), 24-43 -> PV (K=512, hi half)
    // grid 1408 = 8 XCD x 4 chunks x (4 rows x 11 cols)
    gemm128<128, bf16><<<dim3(1408), blk, 0, stream>>>(
        A2, 1024, /*cw*/11, /*rpx*/4,
        Wqk, 1024, bqk, PQK, 3072, 32, 24,
        Wv,  512,  v_b, PV,  2560, 16);
    attn_k<<<dim3(8192), blk, 0, stream>>>(PQK, PV, Aout);
    // grid 256 = 8 XCD x (4 rows x 8 cols)
    gemm128<64, float><<<dim3(256), blk, 0, stream>>>(
        Aout, 512, /*cw*/8, /*rpx*/4,
        Wo, 512, o_b, out, 512, 16, 8,
        Wo, 512, o_b, PQK, 512, 16);  // target-1 args unused (nx0 covers grid)
}